// Round 13
// baseline (178.682 us; speedup 1.0000x reference)
//
#include <hip/hip_runtime.h>
#include <hip/hip_bf16.h>

typedef short short8 __attribute__((ext_vector_type(8)));
typedef float f32x4 __attribute__((ext_vector_type(4)));
typedef float f32x16 __attribute__((ext_vector_type(16)));

typedef __attribute__((address_space(1))) void as1_void;
typedef __attribute__((address_space(3))) void as3_void;

__device__ __forceinline__ unsigned short f2bf(float f) {
    __hip_bfloat16 h = __float2bfloat16(f);
    return __builtin_bit_cast(unsigned short, h);
}
__device__ __forceinline__ unsigned int pack2(float a, float b) {
    return (unsigned int)f2bf(a) | ((unsigned int)f2bf(b) << 16);
}

// fast base-2 exp (v_exp_f32)
__device__ __forceinline__ float exp2fast(float x) {
    return __builtin_amdgcn_exp2f(x);
}

// pack two f32 -> 2xbf16 in one u32 (no builtin on gfx950; T12 recipe)
__device__ __forceinline__ unsigned int cvtpk(float lo, float hi) {
    unsigned int r;
    asm("v_cvt_pk_bf16_f32 %0, %1, %2" : "=v"(r) : "v"(lo), "v"(hi));
    return r;
}

// v_permlane32_swap_b32: a_hi <-> b_lo. After: a=[a_lo|b_lo], b=[a_hi|b_hi]
// NOTE: only safe when a and b are provably-distinct values (R11 lesson).
__device__ __forceinline__ void plswap(unsigned int& a, unsigned int& b) {
    asm("v_permlane32_swap_b32 %0, %1" : "+v"(a), "+v"(b));
}

// async global->LDS, 16B per lane; lds dest = wave-uniform base + lane*16
__device__ __forceinline__ void gload16(const unsigned short* g, unsigned short* l) {
    __builtin_amdgcn_global_load_lds((as1_void*)g, (as3_void*)l, 16, 0, 0);
}

// ---- W[K][N] fp32 -> WT[N][K] bf16 -----------------------------------------
__global__ __launch_bounds__(256) void transpose_f32_to_bf16(
    const float* __restrict__ W, unsigned short* __restrict__ WT, int K, int N) {
    __shared__ float tile[32][33];
    int tx = threadIdx.x, ty = threadIdx.y;
    int n0 = blockIdx.x * 32, k0 = blockIdx.y * 32;
#pragma unroll
    for (int j = 0; j < 4; ++j)
        tile[ty + j * 8][tx] = W[(size_t)(k0 + ty + j * 8) * N + n0 + tx];
    __syncthreads();
#pragma unroll
    for (int j = 0; j < 4; ++j)
        WT[(size_t)(n0 + ty + j * 8) * K + k0 + tx] = f2bf(tile[tx][ty + j * 8]);
}

// ---- GEMM: C[M,N] = A[M,K] @ Bt[N,K]^T + bias ------------------------------
// MODE 0: A bf16, both operands via global_load_lds; fp32 out, stride N.
// MODE 2: A fp32 reg-staged + converted (fuses x->bf16); qkv split out:
//         cols<1024 -> bf16 q*(0.125*log2e); 1024..2047 -> bf16 k;
//         cols>=2048 -> bf16 vt[(b*1024 + c-2048)][t] (transposed V).
template <int MODE>
__global__ __launch_bounds__(256, 3) void gemm_bt(
    const void* __restrict__ A,
    const unsigned short* __restrict__ Bt,
    const float* __restrict__ bias,
    void* __restrict__ out0,
    unsigned short* __restrict__ out1,
    int M, int N, int K) {
    __shared__ unsigned short sA[128 * 32];
    __shared__ unsigned short sB[128 * 32];
    const int tid = threadIdx.x;
    const int lane = tid & 63;
    const int w = tid >> 6;
    const int wr = (w >> 1) * 64;
    const int wc = (w & 1) * 64;
    const size_t arow0 = (size_t)blockIdx.x * 128;
    const size_t brow0 = (size_t)blockIdx.y * 128;

    const int grow = (w << 5) + (lane >> 2);
    const int gcol = (lane & 3) << 3;
    const unsigned short* pA0 =
        (const unsigned short*)A + (arow0 + grow) * (size_t)K + gcol;
    const float* pAf = (const float*)A + (arow0 + grow) * (size_t)K + gcol;
    const unsigned short* pB0 = Bt + (brow0 + grow) * (size_t)K + gcol;
    unsigned short* lA = sA + (w << 10);
    unsigned short* lB = sB + (w << 10);

    f32x4 acc[4][4] = {};
    const int fr = lane & 15;
    const int fk = (lane >> 4) << 3;

    for (int k0 = 0; k0 < K; k0 += 32) {
        __syncthreads();
        if constexpr (MODE == 0) {
            gload16(pA0 + k0, lA);
            gload16(pA0 + 16 * (size_t)K + k0, lA + 512);
            gload16(pB0 + k0, lB);
            gload16(pB0 + 16 * (size_t)K + k0, lB + 512);
        } else {
            float4 xa0 = *(const float4*)(pAf + k0);
            float4 xa1 = *(const float4*)(pAf + k0 + 4);
            float4 xb0 = *(const float4*)(pAf + 16 * (size_t)K + k0);
            float4 xb1 = *(const float4*)(pAf + 16 * (size_t)K + k0 + 4);
            gload16(pB0 + k0, lB);
            gload16(pB0 + 16 * (size_t)K + k0, lB + 512);
            uint4 w0 = make_uint4(pack2(xa0.x, xa0.y), pack2(xa0.z, xa0.w),
                                  pack2(xa1.x, xa1.y), pack2(xa1.z, xa1.w));
            uint4 w1 = make_uint4(pack2(xb0.x, xb0.y), pack2(xb0.z, xb0.w),
                                  pack2(xb1.x, xb1.y), pack2(xb1.z, xb1.w));
            *(uint4*)&sA[grow * 32 + gcol] = w0;
            *(uint4*)&sA[(grow + 16) * 32 + gcol] = w1;
        }
        __syncthreads();

        short8 af[4], bfr[4];
#pragma unroll
        for (int i = 0; i < 4; ++i)
            af[i] = *(const short8*)&sA[(wr + i * 16 + fr) * 32 + fk];
#pragma unroll
        for (int i = 0; i < 4; ++i)
            bfr[i] = *(const short8*)&sB[(wc + i * 16 + fr) * 32 + fk];
#pragma unroll
        for (int mi = 0; mi < 4; ++mi)
#pragma unroll
            for (int ni = 0; ni < 4; ++ni)
                acc[mi][ni] = __builtin_amdgcn_mfma_f32_16x16x32_bf16(
                    af[mi], bfr[ni], acc[mi][ni], 0, 0, 0);
    }

    const int fq = (lane >> 4) << 2;
    if constexpr (MODE == 0) {
#pragma unroll
        for (int mi = 0; mi < 4; ++mi)
#pragma unroll
            for (int ni = 0; ni < 4; ++ni) {
                size_t r = arow0 + wr + mi * 16 + fq;
                size_t c = brow0 + wc + ni * 16 + fr;
                float bv = bias[c];
#pragma unroll
                for (int j = 0; j < 4; ++j)
                    ((float*)out0)[(r + j) * (size_t)N + c] = acc[mi][ni][j] + bv;
            }
    } else {
        const bool isv = (int)(brow0 + wc) >= 2048;
        if (isv) {
#pragma unroll
            for (int mi = 0; mi < 4; ++mi)
#pragma unroll
                for (int ni = 0; ni < 4; ++ni) {
                    int c = (int)brow0 + wc + ni * 16 + fr;
                    float bv = bias[c];
                    int cv = c - 2048;
                    int r0 = (int)arow0 + wr + mi * 16 + fq;
                    int bb = r0 >> 11, t0 = r0 & 2047;
                    unsigned int lo = pack2(acc[mi][ni][0] + bv, acc[mi][ni][1] + bv);
                    unsigned int hi = pack2(acc[mi][ni][2] + bv, acc[mi][ni][3] + bv);
                    *(uint2*)&out1[(((size_t)(bb * 1024 + cv)) << 11) + t0] =
                        make_uint2(lo, hi);
                }
        } else {
            // q columns: fold 1/sqrt(D) * log2(e) so attention runs in exp2 domain
            const float qs = ((int)(brow0 + wc) < 1024) ? 0.125f * 1.4426950408889634f
                                                        : 1.0f;
#pragma unroll
            for (int mi = 0; mi < 4; ++mi)
#pragma unroll
                for (int ni = 0; ni < 4; ++ni) {
                    size_t r = arow0 + wr + mi * 16 + fq;
                    size_t c = brow0 + wc + ni * 16 + fr;
                    float bv = bias[c];
#pragma unroll
                    for (int j = 0; j < 4; ++j)
                        ((unsigned short*)out0)[(r + j) * 2048 + c] =
                            f2bf((acc[mi][ni][j] + bv) * qs);
                }
        }
    }
}

// ---- MFMA flash attention (swapped QK^T, 32x32x16, in-register softmax) ----
// Block: ONE 128-row q-tile (4 waves x 32 rows); grid = BH*16, heavy-first.
// s-tiles of 64; K,V^T double-buffered in swizzled LDS (one barrier/tile).
// Swapped S = mfma(K,Q): q=lane&31, s=reg-pattern -> row softmax is in-reg
// fmax + one cross-half shfl; P->PV refragment via 16 cvt_pk + 8 permlane32
// (no P LDS round-trip). l via MFMA-ones; defer-max rescale (T13).
__global__ __launch_bounds__(256, 2) void attn_mfma(
    const unsigned short* __restrict__ qk,  // [B*T][2048] bf16 (q*scale | k)
    const unsigned short* __restrict__ vt,  // [(b*1024+h*64+d)][T] bf16
    unsigned short* __restrict__ y,         // [B*T][1024] bf16
    int BH) {
    constexpr int T = 2048;
    constexpr float THR = 8.0f;  // exp2-domain defer threshold

    __shared__ __align__(16) unsigned short sK[2][64 * 64];
    __shared__ __align__(16) unsigned short sV[2][64 * 64];  // V^T tile [d][s]

    const int tid = threadIdx.x;
    const int lane = tid & 63;
    const int w = tid >> 6;
    const int l31 = lane & 31;
    const int b5 = lane >> 5;

    const int bh = blockIdx.x % BH;
    const int qt = 15 - blockIdx.x / BH;  // heavy q-tiles dispatched first
    const int b = bh >> 4;
    const int h = bh & 15;
    const int q0 = qt << 7;
    const int qw0 = q0 + w * 32;

    const unsigned short* kbase = qk + ((size_t)(b * T)) * 2048 + 1024 + h * 64;
    const unsigned short* vbase = vt + ((size_t)(b * 1024 + h * 64)) * 2048;

    const int srow = tid >> 3;   // staging row 0..31 (+32)
    const int c16 = tid & 7;     // 16B column within 128B row
    const int swz = ((c16 ^ (srow & 7)) << 3);

    short8 vones;
#pragma unroll
    for (int i = 0; i < 8; ++i) vones[i] = (short)0x3F80;  // bf16 1.0

    // Q fragments (B-operand): row q = qw0+l31, k(d) = b5*8 + kc*16
    short8 aq[4];
    {
        const unsigned short* qbase =
            qk + ((size_t)(b * T + qw0 + l31)) * 2048 + h * 64;
#pragma unroll
        for (int kc = 0; kc < 4; ++kc)
            aq[kc] = *(const short8*)(qbase + b5 * 8 + kc * 16);
    }

    f32x16 O0 = {}, O1 = {};
    f32x16 l_st = {};
    float m_st = -1e30f;

    const int nt = (q0 + 128) >> 6;

    uint4 kd0, kd1, vd0, vd1;
    kd0 = *(const uint4*)(kbase + (size_t)(srow) * 2048 + c16 * 8);
    kd1 = *(const uint4*)(kbase + (size_t)(srow + 32) * 2048 + c16 * 8);
    vd0 = *(const uint4*)(vbase + (size_t)srow * 2048 + c16 * 8);
    vd1 = *(const uint4*)(vbase + (size_t)(srow + 32) * 2048 + c16 * 8);
    *(uint4*)&sK[0][srow * 64 + swz] = kd0;
    *(uint4*)&sK[0][(srow + 32) * 64 + swz] = kd1;
    *(uint4*)&sV[0][srow * 64 + swz] = vd0;
    *(uint4*)&sV[0][(srow + 32) * 64 + swz] = vd1;
    __syncthreads();

    int cur = 0;
    for (int it = 0; it < nt; ++it) {
        const int s0 = it << 6;
        const bool haveNext = (it + 1 < nt);
        if (haveNext) {
            const int s1 = s0 + 64;
            kd0 = *(const uint4*)(kbase + (size_t)(s1 + srow) * 2048 + c16 * 8);
            kd1 = *(const uint4*)(kbase + (size_t)(s1 + srow + 32) * 2048 + c16 * 8);
            vd0 = *(const uint4*)(vbase + (size_t)srow * 2048 + s1 + c16 * 8);
            vd1 = *(const uint4*)(vbase + (size_t)(srow + 32) * 2048 + s1 + c16 * 8);
        }
        const unsigned short* sKc = sK[cur];
        const unsigned short* sVc = sV[cur];

        if (s0 <= qw0 + 31) {  // not fully masked for this wave
            // ---- S^T = K·Q^T via swapped mfma: q = lane&31, s = reg-pattern
            f32x16 sacc[2] = {};
            __builtin_amdgcn_s_setprio(1);
#pragma unroll
            for (int kc = 0; kc < 4; ++kc) {
#pragma unroll
                for (int ni = 0; ni < 2; ++ni) {
                    const int row = ni * 32 + l31;
                    short8 akf = *(const short8*)&sKc[row * 64 +
                                                      (((b5 + kc * 2) ^ (row & 7))
                                                       << 3)];
                    sacc[ni] = __builtin_amdgcn_mfma_f32_32x32x16_bf16(
                        akf, aq[kc], sacc[ni], 0, 0, 0);
                }
            }
            __builtin_amdgcn_s_setprio(0);

            // ---- causal mask (diagonal tiles only) ----
            const bool needMask = (s0 + 63 > qw0);  // wave-uniform
            const int qg = qw0 + l31;
            if (needMask) {
#pragma unroll
                for (int ni = 0; ni < 2; ++ni)
#pragma unroll
                    for (int reg = 0; reg < 16; ++reg) {
                        const int sg = s0 + ni * 32 + (reg & 3) + 8 * (reg >> 2) +
                                       4 * b5;
                        sacc[ni][reg] = (sg <= qg) ? sacc[ni][reg] : -INFINITY;
                    }
            }

            // ---- row max: 31 in-reg fmax + one cross-half exchange ----
            float mx = sacc[0][0];
#pragma unroll
            for (int reg = 1; reg < 16; ++reg) mx = fmaxf(mx, sacc[0][reg]);
#pragma unroll
            for (int reg = 0; reg < 16; ++reg) mx = fmaxf(mx, sacc[1][reg]);
            mx = fmaxf(mx, __shfl_xor(mx, 32));  // lanes l<->l+32 hold same q

            // ---- defer-max ----
            const bool resc = __any(mx > m_st + THR);
            float f_l = 1.0f;
            if (resc) {
                const float mn = fmaxf(m_st, mx);
                f_l = exp2fast(m_st - mn);
                m_st = mn;
            }

            // ---- P = exp2(S - m) in-register ----
#pragma unroll
            for (int ni = 0; ni < 2; ++ni)
#pragma unroll
                for (int reg = 0; reg < 16; ++reg)
                    sacc[ni][reg] = exp2fast(sacc[ni][reg] - m_st);

            // ---- refragment P for PV: per 16-s chunk: 4 cvt_pk + 2 permlane
            short8 pa[4];
#pragma unroll
            for (int c = 0; c < 4; ++c) {
                const int ni = c >> 1;
                const int off = (c & 1) * 8;
                unsigned int pk01 = cvtpk(sacc[ni][off + 0], sacc[ni][off + 1]);
                unsigned int pk23 = cvtpk(sacc[ni][off + 2], sacc[ni][off + 3]);
                unsigned int pk45 = cvtpk(sacc[ni][off + 4], sacc[ni][off + 5]);
                unsigned int pk67 = cvtpk(sacc[ni][off + 6], sacc[ni][off + 7]);
                plswap(pk01, pk45);  // -> slot0 (pk01), slot2 (pk45)
                plswap(pk23, pk67);  // -> slot1 (pk23), slot3 (pk67)
                uint4 u = make_uint4(pk01, pk23, pk45, pk67);
                pa[c] = __builtin_bit_cast(short8, u);
            }

            // ---- rescale O / l (resc tiles only; f transposed l31->regpat)
            if (resc) {
                const int fil = __builtin_bit_cast(int, f_l);
#pragma unroll
                for (int reg = 0; reg < 16; ++reg) {
                    const int qpat = (reg & 3) + 8 * (reg >> 2) + 4 * b5;
                    const float fq = __builtin_bit_cast(
                        float, __builtin_amdgcn_ds_bpermute(
                                   (qpat + (lane & 32)) << 2, fil));
                    O0[reg] *= fq;
                    O1[reg] *= fq;
                    l_st[reg] *= fq;
                }
            }

            // ---- l += rowsum(P) via MFMA-ones; O += P @ V ----
            f32x16 lacc = {};
            __builtin_amdgcn_s_setprio(1);
#pragma unroll
            for (int c = 0; c < 4; ++c) {
                lacc = __builtin_amdgcn_mfma_f32_32x32x16_bf16(
                    pa[c], vones, lacc, 0, 0, 0);
                {
                    const int row = l31;  // di = 0
                    short8 bvf = *(const short8*)&sVc[row * 64 +
                                                      (((c * 2 + b5) ^ (row & 7))
                                                       << 3)];
                    O0 = __builtin_amdgcn_mfma_f32_32x32x16_bf16(
                        pa[c], bvf, O0, 0, 0, 0);
                }
                {
                    const int row = 32 + l31;  // di = 1
                    short8 bvf = *(const short8*)&sVc[row * 64 +
                                                      (((c * 2 + b5) ^ (row & 7))
                                                       << 3)];
                    O1 = __builtin_amdgcn_mfma_f32_32x32x16_bf16(
                        pa[c], bvf, O1, 0, 0, 0);
                }
            }
            __builtin_amdgcn_s_setprio(0);
#pragma unroll
            for (int reg = 0; reg < 16; ++reg) l_st[reg] += lacc[reg];
        }

        // write next tile into the other buffer (overlaps compute above)
        if (haveNext) {
            unsigned short* sKn = sK[cur ^ 1];
            unsigned short* sVn = sV[cur ^ 1];
            *(uint4*)&sKn[srow * 64 + swz] = kd0;
            *(uint4*)&sKn[(srow + 32) * 64 + swz] = kd1;
            *(uint4*)&sVn[srow * 64 + swz] = vd0;
            *(uint4*)&sVn[(srow + 32) * 64 + swz] = vd1;
        }
        __syncthreads();  // publish next buf + protect current buf
        cur ^= 1;
    }

    // ---- normalize + write: q = qw0 + regpat, d = di*32 + l31 ----
#pragma unroll
    for (int reg = 0; reg < 16; ++reg) {
        const int qpat = (reg & 3) + 8 * (reg >> 2) + 4 * b5;
        const float inv = 1.0f / l_st[reg];
        const size_t base = (size_t)(b * T + qw0 + qpat) * 1024 + h * 64 + l31;
        y[base] = f2bf(O0[reg] * inv);
        y[base + 32] = f2bf(O1[reg] * inv);
    }
}

extern "C" void kernel_launch(void* const* d_in, const int* in_sizes, int n_in,
                              void* d_out, int out_size, void* d_ws, size_t ws_size,
                              hipStream_t stream) {
    const float* x      = (const float*)d_in[0];
    const float* w_attn = (const float*)d_in[1];
    const float* b_attn = (const float*)d_in[2];
    const float* w_proj = (const float*)d_in[3];
    const float* b_proj = (const float*)d_in[4];

    const int C = 1024, T = 2048, H = 16;
    const int B = in_sizes[0] / (T * C);
    const int M = B * T;

    // workspace (ushorts): yb | wTa | wTp | qk | vt
    unsigned short* yb  = (unsigned short*)d_ws;          // M*C (attn out)
    unsigned short* wTa = yb + (size_t)M * C;             // 3C x C
    unsigned short* wTp = wTa + (size_t)3 * C * C;        // C x C
    unsigned short* qkb = wTp + (size_t)C * C;            // M x 2C
    unsigned short* vtb = qkb + (size_t)M * 2 * C;        // B*1024 x T

    transpose_f32_to_bf16<<<dim3(3 * C / 32, C / 32), dim3(32, 8), 0, stream>>>(
        w_attn, wTa, C, 3 * C);
    transpose_f32_to_bf16<<<dim3(C / 32, C / 32), dim3(32, 8), 0, stream>>>(
        w_proj, wTp, C, C);
    gemm_bt<2><<<dim3(M / 128, (3 * C) / 128), 256, 0, stream>>>(
        (const void*)x, wTa, b_attn, (void*)qkb, vtb, M, 3 * C, C);
    attn_mfma<<<dim3((B * H) * 16), 256, 0, stream>>>(qkb, vtb, yb, B * H);
    gemm_bt<0><<<dim3(M / 128, C / 128), 256, 0, stream>>>(
        (const void*)yb, wTp, b_proj, d_out, nullptr, M, C, C);
}

// Round 14
// 168.252 us; speedup vs baseline: 1.0620x; 1.0620x over previous
//
#include <hip/hip_runtime.h>
#include <hip/hip_bf16.h>

typedef short short8 __attribute__((ext_vector_type(8)));
typedef float f32x4 __attribute__((ext_vector_type(4)));
typedef float f32x16 __attribute__((ext_vector_type(16)));

typedef __attribute__((address_space(1))) void as1_void;
typedef __attribute__((address_space(3))) void as3_void;

__device__ __forceinline__ unsigned short f2bf(float f) {
    __hip_bfloat16 h = __float2bfloat16(f);
    return __builtin_bit_cast(unsigned short, h);
}

// fast base-2 exp (v_exp_f32)
__device__ __forceinline__ float exp2fast(float x) {
    return __builtin_amdgcn_exp2f(x);
}

// pack two f32 -> 2xbf16 in one u32 (no builtin on gfx950; T12 recipe)
__device__ __forceinline__ unsigned int cvtpk(float lo, float hi) {
    unsigned int r;
    asm("v_cvt_pk_bf16_f32 %0, %1, %2" : "=v"(r) : "v"(lo), "v"(hi));
    return r;
}

// v_permlane32_swap_b32: a_hi <-> b_lo. After: a=[a_lo|b_lo], b=[a_hi|b_hi]
// NOTE: only safe when a and b are provably-distinct values (R11 lesson).
__device__ __forceinline__ void plswap(unsigned int& a, unsigned int& b) {
    asm("v_permlane32_swap_b32 %0, %1" : "+v"(a), "+v"(b));
}

// async global->LDS, 16B per lane; lds dest = wave-uniform base + lane*16
__device__ __forceinline__ void gload16(const unsigned short* g, unsigned short* l) {
    __builtin_amdgcn_global_load_lds((as1_void*)g, (as3_void*)l, 16, 0, 0);
}

// ---- fp32 -> bf16 elementwise ----------------------------------------------
__global__ __launch_bounds__(256) void conv_f32_to_bf16(
    const float* __restrict__ in, unsigned short* __restrict__ out, int n4) {
    int i = blockIdx.x * 256 + threadIdx.x;
    if (i >= n4) return;
    float4 v = ((const float4*)in)[i];
    ushort4 o;
    o.x = f2bf(v.x); o.y = f2bf(v.y); o.z = f2bf(v.z); o.w = f2bf(v.w);
    ((ushort4*)out)[i] = o;
}

// ---- W[K][N] fp32 -> WT[N][K] bf16 -----------------------------------------
__global__ __launch_bounds__(256) void transpose_f32_to_bf16(
    const float* __restrict__ W, unsigned short* __restrict__ WT, int K, int N) {
    __shared__ float tile[32][33];
    int tx = threadIdx.x, ty = threadIdx.y;
    int n0 = blockIdx.x * 32, k0 = blockIdx.y * 32;
#pragma unroll
    for (int j = 0; j < 4; ++j)
        tile[ty + j * 8][tx] = W[(size_t)(k0 + ty + j * 8) * N + n0 + tx];
    __syncthreads();
#pragma unroll
    for (int j = 0; j < 4; ++j)
        WT[(size_t)(n0 + ty + j * 8) * K + k0 + tx] = f2bf(tile[tx][ty + j * 8]);
}

// ---- GEMM: C[M,N] = A[M,K]bf16 @ Bt[N,K]^T + bias --------------------------
// BK=64, global_load_lds staging with XOR-swizzled layout (pre-swizzled
// global source column chunk^(row&7); same XOR on fragment reads ->
// conflict-free ds_read_b128). MODE 0: fp32 out, stride N.
// MODE 2: qkv split: cols<1024 -> bf16 q*(0.125*log2e); 1024..2047 -> bf16 k;
//         cols>=2048 -> bf16 vt[(b*1024 + c-2048)][t] (transposed V).
template <int MODE>
__global__ __launch_bounds__(256, 2) void gemm_bt(
    const unsigned short* __restrict__ A,
    const unsigned short* __restrict__ Bt,
    const float* __restrict__ bias,
    void* __restrict__ out0,
    unsigned short* __restrict__ out1,
    int M, int N, int K) {
    __shared__ unsigned short sA[128 * 64];
    __shared__ unsigned short sB[128 * 64];
    const int tid = threadIdx.x;
    const int lane = tid & 63;
    const int w = tid >> 6;
    const int wr = (w >> 1) * 64;
    const int wc = (w & 1) * 64;
    const size_t arow0 = (size_t)blockIdx.x * 128;
    const size_t brow0 = (size_t)blockIdx.y * 128;

    // staging: wave w owns rows [w*32, w*32+32); issue j covers rows +j*8.
    // lane l -> row w*32 + j*8 + (l>>3), LDS chunk (l&7); global column
    // chunk is XOR-swizzled: (l&7) ^ ((l>>3)&7)  (row&7 == (l>>3)&7).
    const int grow = (w << 5) + (lane >> 3);
    const int gcolswz = (((lane & 7) ^ ((lane >> 3) & 7)) << 3);
    const unsigned short* pA0 = A + (arow0 + grow) * (size_t)K + gcolswz;
    const unsigned short* pB0 = Bt + (brow0 + grow) * (size_t)K + gcolswz;
    unsigned short* lA = sA + (w << 11);  // w*32*64
    unsigned short* lB = sB + (w << 11);

    f32x4 acc[4][4] = {};
    const int fr = lane & 15;
    const int g = lane >> 4;  // 0..3 -> k-chunk within 32-wide half

    for (int k0 = 0; k0 < K; k0 += 64) {
        __syncthreads();
#pragma unroll
        for (int j = 0; j < 4; ++j) {
            gload16(pA0 + (size_t)(j * 8) * K + k0, lA + j * 512);
            gload16(pB0 + (size_t)(j * 8) * K + k0, lB + j * 512);
        }
        __syncthreads();

#pragma unroll
        for (int kc = 0; kc < 2; ++kc) {
            short8 af[4], bfr[4];
#pragma unroll
            for (int i = 0; i < 4; ++i) {
                const int row = wr + i * 16 + fr;
                af[i] = *(const short8*)&sA[row * 64 +
                                            (((kc * 4 + g) ^ (row & 7)) << 3)];
            }
#pragma unroll
            for (int i = 0; i < 4; ++i) {
                const int row = wc + i * 16 + fr;
                bfr[i] = *(const short8*)&sB[row * 64 +
                                             (((kc * 4 + g) ^ (row & 7)) << 3)];
            }
#pragma unroll
            for (int mi = 0; mi < 4; ++mi)
#pragma unroll
                for (int ni = 0; ni < 4; ++ni)
                    acc[mi][ni] = __builtin_amdgcn_mfma_f32_16x16x32_bf16(
                        af[mi], bfr[ni], acc[mi][ni], 0, 0, 0);
        }
    }

    const int fq = (lane >> 4) << 2;
    if constexpr (MODE == 0) {
#pragma unroll
        for (int mi = 0; mi < 4; ++mi)
#pragma unroll
            for (int ni = 0; ni < 4; ++ni) {
                size_t r = arow0 + wr + mi * 16 + fq;
                size_t c = brow0 + wc + ni * 16 + fr;
                float bv = bias[c];
#pragma unroll
                for (int j = 0; j < 4; ++j)
                    ((float*)out0)[(r + j) * (size_t)N + c] = acc[mi][ni][j] + bv;
            }
    } else {
        const bool isv = (int)(brow0 + wc) >= 2048;
        if (isv) {
#pragma unroll
            for (int mi = 0; mi < 4; ++mi)
#pragma unroll
                for (int ni = 0; ni < 4; ++ni) {
                    int c = (int)brow0 + wc + ni * 16 + fr;
                    float bv = bias[c];
                    int cv = c - 2048;
                    int r0 = (int)arow0 + wr + mi * 16 + fq;
                    int bb = r0 >> 11, t0 = r0 & 2047;
                    unsigned int lo = (unsigned int)f2bf(acc[mi][ni][0] + bv) |
                                      ((unsigned int)f2bf(acc[mi][ni][1] + bv) << 16);
                    unsigned int hi = (unsigned int)f2bf(acc[mi][ni][2] + bv) |
                                      ((unsigned int)f2bf(acc[mi][ni][3] + bv) << 16);
                    *(uint2*)&out1[(((size_t)(bb * 1024 + cv)) << 11) + t0] =
                        make_uint2(lo, hi);
                }
        } else {
            // q columns: fold 1/sqrt(D) * log2(e) so attention runs in exp2 domain
            const float qs = ((int)(brow0 + wc) < 1024) ? 0.125f * 1.4426950408889634f
                                                        : 1.0f;
#pragma unroll
            for (int mi = 0; mi < 4; ++mi)
#pragma unroll
                for (int ni = 0; ni < 4; ++ni) {
                    size_t r = arow0 + wr + mi * 16 + fq;
                    size_t c = brow0 + wc + ni * 16 + fr;
                    float bv = bias[c];
#pragma unroll
                    for (int j = 0; j < 4; ++j)
                        ((unsigned short*)out0)[(r + j) * 2048 + c] =
                            f2bf((acc[mi][ni][j] + bv) * qs);
                }
        }
    }
}

// ---- MFMA flash attention (swapped QK^T, 32x32x16, in-register softmax) ----
// Block: ONE 128-row q-tile (4 waves x 32 rows); grid = BH*16, heavy-first.
// s-tiles of 64; K,V^T double-buffered in swizzled LDS (one barrier/tile).
// Swapped S = mfma(K,Q): q=lane&31, s=reg-pattern -> row softmax is in-reg
// fmax + one cross-half shfl; P->PV refragment via 16 cvt_pk + 8 permlane32
// (no P LDS round-trip). l via MFMA-ones; defer-max rescale (T13).
__global__ __launch_bounds__(256, 2) void attn_mfma(
    const unsigned short* __restrict__ qk,  // [B*T][2048] bf16 (q*scale | k)
    const unsigned short* __restrict__ vt,  // [(b*1024+h*64+d)][T] bf16
    unsigned short* __restrict__ y,         // [B*T][1024] bf16
    int BH) {
    constexpr int T = 2048;
    constexpr float THR = 8.0f;  // exp2-domain defer threshold

    __shared__ __align__(16) unsigned short sK[2][64 * 64];
    __shared__ __align__(16) unsigned short sV[2][64 * 64];  // V^T tile [d][s]

    const int tid = threadIdx.x;
    const int lane = tid & 63;
    const int w = tid >> 6;
    const int l31 = lane & 31;
    const int b5 = lane >> 5;

    const int bh = blockIdx.x % BH;
    const int qt = 15 - blockIdx.x / BH;  // heavy q-tiles dispatched first
    const int b = bh >> 4;
    const int h = bh & 15;
    const int q0 = qt << 7;
    const int qw0 = q0 + w * 32;

    const unsigned short* kbase = qk + ((size_t)(b * T)) * 2048 + 1024 + h * 64;
    const unsigned short* vbase = vt + ((size_t)(b * 1024 + h * 64)) * 2048;

    const int srow = tid >> 3;   // staging row 0..31 (+32)
    const int c16 = tid & 7;     // 16B column within 128B row
    const int swz = ((c16 ^ (srow & 7)) << 3);

    short8 vones;
#pragma unroll
    for (int i = 0; i < 8; ++i) vones[i] = (short)0x3F80;  // bf16 1.0

    // Q fragments (B-operand): row q = qw0+l31, k(d) = b5*8 + kc*16
    short8 aq[4];
    {
        const unsigned short* qbase =
            qk + ((size_t)(b * T + qw0 + l31)) * 2048 + h * 64;
#pragma unroll
        for (int kc = 0; kc < 4; ++kc)
            aq[kc] = *(const short8*)(qbase + b5 * 8 + kc * 16);
    }

    f32x16 O0 = {}, O1 = {};
    f32x16 l_st = {};
    float m_st = -1e30f;

    const int nt = (q0 + 128) >> 6;

    uint4 kd0, kd1, vd0, vd1;
    kd0 = *(const uint4*)(kbase + (size_t)(srow) * 2048 + c16 * 8);
    kd1 = *(const uint4*)(kbase + (size_t)(srow + 32) * 2048 + c16 * 8);
    vd0 = *(const uint4*)(vbase + (size_t)srow * 2048 + c16 * 8);
    vd1 = *(const uint4*)(vbase + (size_t)(srow + 32) * 2048 + c16 * 8);
    *(uint4*)&sK[0][srow * 64 + swz] = kd0;
    *(uint4*)&sK[0][(srow + 32) * 64 + swz] = kd1;
    *(uint4*)&sV[0][srow * 64 + swz] = vd0;
    *(uint4*)&sV[0][(srow + 32) * 64 + swz] = vd1;
    __syncthreads();

    int cur = 0;
    for (int it = 0; it < nt; ++it) {
        const int s0 = it << 6;
        const bool haveNext = (it + 1 < nt);
        if (haveNext) {
            const int s1 = s0 + 64;
            kd0 = *(const uint4*)(kbase + (size_t)(s1 + srow) * 2048 + c16 * 8);
            kd1 = *(const uint4*)(kbase + (size_t)(s1 + srow + 32) * 2048 + c16 * 8);
            vd0 = *(const uint4*)(vbase + (size_t)srow * 2048 + s1 + c16 * 8);
            vd1 = *(const uint4*)(vbase + (size_t)(srow + 32) * 2048 + s1 + c16 * 8);
        }
        const unsigned short* sKc = sK[cur];
        const unsigned short* sVc = sV[cur];

        if (s0 <= qw0 + 31) {  // not fully masked for this wave
            // ---- S^T = K·Q^T via swapped mfma: q = lane&31, s = reg-pattern
            f32x16 sacc[2] = {};
            __builtin_amdgcn_s_setprio(1);
#pragma unroll
            for (int kc = 0; kc < 4; ++kc) {
#pragma unroll
                for (int ni = 0; ni < 2; ++ni) {
                    const int row = ni * 32 + l31;
                    short8 akf = *(const short8*)&sKc[row * 64 +
                                                      (((b5 + kc * 2) ^ (row & 7))
                                                       << 3)];
                    sacc[ni] = __builtin_amdgcn_mfma_f32_32x32x16_bf16(
                        akf, aq[kc], sacc[ni], 0, 0, 0);
                }
            }
            __builtin_amdgcn_s_setprio(0);

            // ---- causal mask (diagonal tiles only) ----
            const bool needMask = (s0 + 63 > qw0);  // wave-uniform
            const int qg = qw0 + l31;
            if (needMask) {
#pragma unroll
                for (int ni = 0; ni < 2; ++ni)
#pragma unroll
                    for (int reg = 0; reg < 16; ++reg) {
                        const int sg = s0 + ni * 32 + (reg & 3) + 8 * (reg >> 2) +
                                       4 * b5;
                        sacc[ni][reg] = (sg <= qg) ? sacc[ni][reg] : -INFINITY;
                    }
            }

            // ---- row max: 31 in-reg fmax + one cross-half exchange ----
            float mx = sacc[0][0];
#pragma unroll
            for (int reg = 1; reg < 16; ++reg) mx = fmaxf(mx, sacc[0][reg]);
#pragma unroll
            for (int reg = 0; reg < 16; ++reg) mx = fmaxf(mx, sacc[1][reg]);
            mx = fmaxf(mx, __shfl_xor(mx, 32));  // lanes l<->l+32 hold same q

            // ---- defer-max ----
            const bool resc = __any(mx > m_st + THR);
            float f_l = 1.0f;
            if (resc) {
                const float mn = fmaxf(m_st, mx);
                f_l = exp2fast(m_st - mn);
                m_st = mn;
            }

            // ---- P = exp2(S - m) in-register ----
#pragma unroll
            for (int ni = 0; ni < 2; ++ni)
#pragma unroll
                for (int reg = 0; reg < 16; ++reg)
                    sacc[ni][reg] = exp2fast(sacc[ni][reg] - m_st);

            // ---- refragment P for PV: per 16-s chunk: 4 cvt_pk + 2 permlane
            short8 pa[4];
#pragma unroll
            for (int c = 0; c < 4; ++c) {
                const int ni = c >> 1;
                const int off = (c & 1) * 8;
                unsigned int pk01 = cvtpk(sacc[ni][off + 0], sacc[ni][off + 1]);
                unsigned int pk23 = cvtpk(sacc[ni][off + 2], sacc[ni][off + 3]);
                unsigned int pk45 = cvtpk(sacc[ni][off + 4], sacc[ni][off + 5]);
                unsigned int pk67 = cvtpk(sacc[ni][off + 6], sacc[ni][off + 7]);
                plswap(pk01, pk45);  // -> slot0 (pk01), slot2 (pk45)
                plswap(pk23, pk67);  // -> slot1 (pk23), slot3 (pk67)
                uint4 u = make_uint4(pk01, pk23, pk45, pk67);
                pa[c] = __builtin_bit_cast(short8, u);
            }

            // ---- rescale O / l (resc tiles only; f transposed l31->regpat)
            if (resc) {
                const int fil = __builtin_bit_cast(int, f_l);
#pragma unroll
                for (int reg = 0; reg < 16; ++reg) {
                    const int qpat = (reg & 3) + 8 * (reg >> 2) + 4 * b5;
                    const float fq = __builtin_bit_cast(
                        float, __builtin_amdgcn_ds_bpermute(
                                   (qpat + (lane & 32)) << 2, fil));
                    O0[reg] *= fq;
                    O1[reg] *= fq;
                    l_st[reg] *= fq;
                }
            }

            // ---- l += rowsum(P) via MFMA-ones; O += P @ V ----
            f32x16 lacc = {};
            __builtin_amdgcn_s_setprio(1);
#pragma unroll
            for (int c = 0; c < 4; ++c) {
                lacc = __builtin_amdgcn_mfma_f32_32x32x16_bf16(
                    pa[c], vones, lacc, 0, 0, 0);
                {
                    const int row = l31;  // di = 0
                    short8 bvf = *(const short8*)&sVc[row * 64 +
                                                      (((c * 2 + b5) ^ (row & 7))
                                                       << 3)];
                    O0 = __builtin_amdgcn_mfma_f32_32x32x16_bf16(
                        pa[c], bvf, O0, 0, 0, 0);
                }
                {
                    const int row = 32 + l31;  // di = 1
                    short8 bvf = *(const short8*)&sVc[row * 64 +
                                                      (((c * 2 + b5) ^ (row & 7))
                                                       << 3)];
                    O1 = __builtin_amdgcn_mfma_f32_32x32x16_bf16(
                        pa[c], bvf, O1, 0, 0, 0);
                }
            }
            __builtin_amdgcn_s_setprio(0);
#pragma unroll
            for (int reg = 0; reg < 16; ++reg) l_st[reg] += lacc[reg];
        }

        // write next tile into the other buffer (overlaps compute above)
        if (haveNext) {
            unsigned short* sKn = sK[cur ^ 1];
            unsigned short* sVn = sV[cur ^ 1];
            *(uint4*)&sKn[srow * 64 + swz] = kd0;
            *(uint4*)&sKn[(srow + 32) * 64 + swz] = kd1;
            *(uint4*)&sVn[srow * 64 + swz] = vd0;
            *(uint4*)&sVn[(srow + 32) * 64 + swz] = vd1;
        }
        __syncthreads();  // publish next buf + protect current buf
        cur ^= 1;
    }

    // ---- normalize + write: q = qw0 + regpat, d = di*32 + l31 ----
#pragma unroll
    for (int reg = 0; reg < 16; ++reg) {
        const int qpat = (reg & 3) + 8 * (reg >> 2) + 4 * b5;
        const float inv = 1.0f / l_st[reg];
        const size_t base = (size_t)(b * T + qw0 + qpat) * 1024 + h * 64 + l31;
        y[base] = f2bf(O0[reg] * inv);
        y[base + 32] = f2bf(O1[reg] * inv);
    }
}

extern "C" void kernel_launch(void* const* d_in, const int* in_sizes, int n_in,
                              void* d_out, int out_size, void* d_ws, size_t ws_size,
                              hipStream_t stream) {
    const float* x      = (const float*)d_in[0];
    const float* w_attn = (const float*)d_in[1];
    const float* b_attn = (const float*)d_in[2];
    const float* w_proj = (const float*)d_in[3];
    const float* b_proj = (const float*)d_in[4];

    const int C = 1024, T = 2048, H = 16;
    const int B = in_sizes[0] / (T * C);
    const int M = B * T;

    // workspace (ushorts): xb | wTa | wTp | qk | vt   (75.5 MB total)
    unsigned short* xb  = (unsigned short*)d_ws;          // M*C
    unsigned short* wTa = xb + (size_t)M * C;             // 3C x C
    unsigned short* wTp = wTa + (size_t)3 * C * C;        // C x C
    unsigned short* qkb = wTp + (size_t)C * C;            // M x 2C
    unsigned short* vtb = qkb + (size_t)M * 2 * C;        // B*1024 x T
    unsigned short* y   = xb;                             // reuse after GEMM1

    int n4 = (M * C) / 4;
    conv_f32_to_bf16<<<(n4 + 255) / 256, 256, 0, stream>>>(x, xb, n4);
    transpose_f32_to_bf16<<<dim3(3 * C / 32, C / 32), dim3(32, 8), 0, stream>>>(
        w_attn, wTa, C, 3 * C);
    transpose_f32_to_bf16<<<dim3(C / 32, C / 32), dim3(32, 8), 0, stream>>>(
        w_proj, wTp, C, C);
    gemm_bt<2><<<dim3(M / 128, (3 * C) / 128), 256, 0, stream>>>(
        xb, wTa, b_attn, (void*)qkb, vtb, M, 3 * C, C);
    attn_mfma<<<dim3((B * H) * 16), 256, 0, stream>>>(qkb, vtb, y, B * H);
    gemm_bt<0><<<dim3(M / 128, C / 128), 256, 0, stream>>>(
        y, wTp, b_proj, d_out, nullptr, M, C, C);
}

// Round 15
// 163.790 us; speedup vs baseline: 1.0909x; 1.0272x over previous
//
#include <hip/hip_runtime.h>
#include <hip/hip_bf16.h>

typedef short short8 __attribute__((ext_vector_type(8)));
typedef float f32x4 __attribute__((ext_vector_type(4)));
typedef float f32x16 __attribute__((ext_vector_type(16)));

typedef __attribute__((address_space(1))) void as1_void;
typedef __attribute__((address_space(3))) void as3_void;

__device__ __forceinline__ unsigned short f2bf(float f) {
    __hip_bfloat16 h = __float2bfloat16(f);
    return __builtin_bit_cast(unsigned short, h);
}

// fast base-2 exp (v_exp_f32)
__device__ __forceinline__ float exp2fast(float x) {
    return __builtin_amdgcn_exp2f(x);
}

// pack two f32 -> 2xbf16 in one u32 (no builtin on gfx950; T12 recipe)
__device__ __forceinline__ unsigned int cvtpk(float lo, float hi) {
    unsigned int r;
    asm("v_cvt_pk_bf16_f32 %0, %1, %2" : "=v"(r) : "v"(lo), "v"(hi));
    return r;
}

// v_permlane32_swap_b32: a_hi <-> b_lo. After: a=[a_lo|b_lo], b=[a_hi|b_hi]
// NOTE: only safe when a and b are provably-distinct values (R11 lesson).
__device__ __forceinline__ void plswap(unsigned int& a, unsigned int& b) {
    asm("v_permlane32_swap_b32 %0, %1" : "+v"(a), "+v"(b));
}

// async global->LDS, 16B per lane; lds dest = wave-uniform base + lane*16
__device__ __forceinline__ void gload16(const unsigned short* g, unsigned short* l) {
    __builtin_amdgcn_global_load_lds((as1_void*)g, (as3_void*)l, 16, 0, 0);
}

// ---- fp32 -> bf16 elementwise ----------------------------------------------
__global__ __launch_bounds__(256) void conv_f32_to_bf16(
    const float* __restrict__ in, unsigned short* __restrict__ out, int n4) {
    int i = blockIdx.x * 256 + threadIdx.x;
    if (i >= n4) return;
    float4 v = ((const float4*)in)[i];
    ushort4 o;
    o.x = f2bf(v.x); o.y = f2bf(v.y); o.z = f2bf(v.z); o.w = f2bf(v.w);
    ((ushort4*)out)[i] = o;
}

// ---- W[K][N] fp32 -> WT[N][K] bf16 -----------------------------------------
__global__ __launch_bounds__(256) void transpose_f32_to_bf16(
    const float* __restrict__ W, unsigned short* __restrict__ WT, int K, int N) {
    __shared__ float tile[32][33];
    int tx = threadIdx.x, ty = threadIdx.y;
    int n0 = blockIdx.x * 32, k0 = blockIdx.y * 32;
#pragma unroll
    for (int j = 0; j < 4; ++j)
        tile[ty + j * 8][tx] = W[(size_t)(k0 + ty + j * 8) * N + n0 + tx];
    __syncthreads();
#pragma unroll
    for (int j = 0; j < 4; ++j)
        WT[(size_t)(n0 + ty + j * 8) * K + k0 + tx] = f2bf(tile[tx][ty + j * 8]);
}

// ---- GEMM: C[M,N] = A[M,K]bf16 @ Bt[N,K]^T + bias --------------------------
// BK=64, global_load_lds staging with XOR-swizzled layout (pre-swizzled
// global source column chunk^(row&7); same XOR on fragment reads ->
// conflict-free ds_read_b128). MODE 0: fp32 out, stride N.
// MODE 2: qkv split: cols<1024 -> bf16 q*(0.125*log2e); 1024..2047 -> bf16 k;
//         cols>=2048 -> bf16 vt[(b*1024 + c-2048)][t] (transposed V).
template <int MODE>
__global__ __launch_bounds__(256, 2) void gemm_bt(
    const unsigned short* __restrict__ A,
    const unsigned short* __restrict__ Bt,
    const float* __restrict__ bias,
    void* __restrict__ out0,
    unsigned short* __restrict__ out1,
    int M, int N, int K) {
    __shared__ unsigned short sA[128 * 64];
    __shared__ unsigned short sB[128 * 64];
    const int tid = threadIdx.x;
    const int lane = tid & 63;
    const int w = tid >> 6;
    const int wr = (w >> 1) * 64;
    const int wc = (w & 1) * 64;
    const size_t arow0 = (size_t)blockIdx.x * 128;
    const size_t brow0 = (size_t)blockIdx.y * 128;

    const int grow = (w << 5) + (lane >> 3);
    const int gcolswz = (((lane & 7) ^ ((lane >> 3) & 7)) << 3);
    const unsigned short* pA0 = A + (arow0 + grow) * (size_t)K + gcolswz;
    const unsigned short* pB0 = Bt + (brow0 + grow) * (size_t)K + gcolswz;
    unsigned short* lA = sA + (w << 11);  // w*32*64
    unsigned short* lB = sB + (w << 11);

    f32x4 acc[4][4] = {};
    const int fr = lane & 15;
    const int g = lane >> 4;  // 0..3 -> k-chunk within 32-wide half

    for (int k0 = 0; k0 < K; k0 += 64) {
        __syncthreads();
#pragma unroll
        for (int j = 0; j < 4; ++j) {
            gload16(pA0 + (size_t)(j * 8) * K + k0, lA + j * 512);
            gload16(pB0 + (size_t)(j * 8) * K + k0, lB + j * 512);
        }
        __syncthreads();

#pragma unroll
        for (int kc = 0; kc < 2; ++kc) {
            short8 af[4], bfr[4];
#pragma unroll
            for (int i = 0; i < 4; ++i) {
                const int row = wr + i * 16 + fr;
                af[i] = *(const short8*)&sA[row * 64 +
                                            (((kc * 4 + g) ^ (row & 7)) << 3)];
            }
#pragma unroll
            for (int i = 0; i < 4; ++i) {
                const int row = wc + i * 16 + fr;
                bfr[i] = *(const short8*)&sB[row * 64 +
                                             (((kc * 4 + g) ^ (row & 7)) << 3)];
            }
#pragma unroll
            for (int mi = 0; mi < 4; ++mi)
#pragma unroll
                for (int ni = 0; ni < 4; ++ni)
                    acc[mi][ni] = __builtin_amdgcn_mfma_f32_16x16x32_bf16(
                        af[mi], bfr[ni], acc[mi][ni], 0, 0, 0);
        }
    }

    const int fq = (lane >> 4) << 2;
    if constexpr (MODE == 0) {
#pragma unroll
        for (int mi = 0; mi < 4; ++mi)
#pragma unroll
            for (int ni = 0; ni < 4; ++ni) {
                size_t r = arow0 + wr + mi * 16 + fq;
                size_t c = brow0 + wc + ni * 16 + fr;
                float bv = bias[c];
#pragma unroll
                for (int j = 0; j < 4; ++j)
                    ((float*)out0)[(r + j) * (size_t)N + c] = acc[mi][ni][j] + bv;
            }
    } else {
        const bool isv = (int)(brow0 + wc) >= 2048;
        if (isv) {
#pragma unroll
            for (int mi = 0; mi < 4; ++mi)
#pragma unroll
                for (int ni = 0; ni < 4; ++ni) {
                    int c = (int)brow0 + wc + ni * 16 + fr;
                    float bv = bias[c];
                    int cv = c - 2048;
                    int r0 = (int)arow0 + wr + mi * 16 + fq;
                    int bb = r0 >> 11, t0 = r0 & 2047;
                    unsigned int lo = (unsigned int)f2bf(acc[mi][ni][0] + bv) |
                                      ((unsigned int)f2bf(acc[mi][ni][1] + bv) << 16);
                    unsigned int hi = (unsigned int)f2bf(acc[mi][ni][2] + bv) |
                                      ((unsigned int)f2bf(acc[mi][ni][3] + bv) << 16);
                    *(uint2*)&out1[(((size_t)(bb * 1024 + cv)) << 11) + t0] =
                        make_uint2(lo, hi);
                }
        } else {
            // q columns: fold 1/sqrt(D) * log2(e) so attention runs in exp2 domain
            const float qs = ((int)(brow0 + wc) < 1024) ? 0.125f * 1.4426950408889634f
                                                        : 1.0f;
#pragma unroll
            for (int mi = 0; mi < 4; ++mi)
#pragma unroll
                for (int ni = 0; ni < 4; ++ni) {
                    size_t r = arow0 + wr + mi * 16 + fq;
                    size_t c = brow0 + wc + ni * 16 + fr;
                    float bv = bias[c];
#pragma unroll
                    for (int j = 0; j < 4; ++j)
                        ((unsigned short*)out0)[(r + j) * 2048 + c] =
                            f2bf((acc[mi][ni][j] + bv) * qs);
                }
        }
    }
}

// ---- MFMA flash attention (swapped QK^T, 32x32x16, in-register softmax) ----
// Block: ONE 128-row q-tile (4 waves x 32 rows); grid = BH*16, heavy-first.
// s-tiles of 64; K,V^T double-buffered in swizzled LDS (one barrier/tile).
// Swapped S = mfma(K,Q): q=lane&31, s=reg-pattern -> row softmax is in-reg
// tree-max (v_max3) + one cross-half shfl; P->PV refragment via 16 cvt_pk +
// 8 permlane32 (no P LDS round-trip). l via MFMA-ones; defer-max (T13).
// launch_bounds(256,3): squeeze regs so 3 waves/SIMD fit (occupancy lever).
__global__ __launch_bounds__(256, 3) void attn_mfma(
    const unsigned short* __restrict__ qk,  // [B*T][2048] bf16 (q*scale | k)
    const unsigned short* __restrict__ vt,  // [(b*1024+h*64+d)][T] bf16
    unsigned short* __restrict__ y,         // [B*T][1024] bf16
    int BH) {
    constexpr int T = 2048;
    constexpr float THR = 8.0f;  // exp2-domain defer threshold

    __shared__ __align__(16) unsigned short sK[2][64 * 64];
    __shared__ __align__(16) unsigned short sV[2][64 * 64];  // V^T tile [d][s]

    const int tid = threadIdx.x;
    const int lane = tid & 63;
    const int w = tid >> 6;
    const int l31 = lane & 31;
    const int b5 = lane >> 5;

    const int bh = blockIdx.x % BH;
    const int qt = 15 - blockIdx.x / BH;  // heavy q-tiles dispatched first
    const int b = bh >> 4;
    const int h = bh & 15;
    const int q0 = qt << 7;
    const int qw0 = q0 + w * 32;

    const unsigned short* kbase = qk + ((size_t)(b * T)) * 2048 + 1024 + h * 64;
    const unsigned short* vbase = vt + ((size_t)(b * 1024 + h * 64)) * 2048;

    const int srow = tid >> 3;   // staging row 0..31 (+32)
    const int c16 = tid & 7;     // 16B column within 128B row
    const int swz = ((c16 ^ (srow & 7)) << 3);

    short8 vones;
#pragma unroll
    for (int i = 0; i < 8; ++i) vones[i] = (short)0x3F80;  // bf16 1.0

    // Q fragments (B-operand): row q = qw0+l31, k(d) = b5*8 + kc*16
    short8 aq[4];
    {
        const unsigned short* qbase =
            qk + ((size_t)(b * T + qw0 + l31)) * 2048 + h * 64;
#pragma unroll
        for (int kc = 0; kc < 4; ++kc)
            aq[kc] = *(const short8*)(qbase + b5 * 8 + kc * 16);
    }

    f32x16 O0 = {}, O1 = {};
    f32x16 l_st = {};
    float m_st = -1e30f;

    const int nt = (q0 + 128) >> 6;

    uint4 kd0, kd1, vd0, vd1;
    kd0 = *(const uint4*)(kbase + (size_t)(srow) * 2048 + c16 * 8);
    kd1 = *(const uint4*)(kbase + (size_t)(srow + 32) * 2048 + c16 * 8);
    vd0 = *(const uint4*)(vbase + (size_t)srow * 2048 + c16 * 8);
    vd1 = *(const uint4*)(vbase + (size_t)(srow + 32) * 2048 + c16 * 8);
    *(uint4*)&sK[0][srow * 64 + swz] = kd0;
    *(uint4*)&sK[0][(srow + 32) * 64 + swz] = kd1;
    *(uint4*)&sV[0][srow * 64 + swz] = vd0;
    *(uint4*)&sV[0][(srow + 32) * 64 + swz] = vd1;
    __syncthreads();

    int cur = 0;
    for (int it = 0; it < nt; ++it) {
        const int s0 = it << 6;
        const bool haveNext = (it + 1 < nt);
        if (haveNext) {
            const int s1 = s0 + 64;
            kd0 = *(const uint4*)(kbase + (size_t)(s1 + srow) * 2048 + c16 * 8);
            kd1 = *(const uint4*)(kbase + (size_t)(s1 + srow + 32) * 2048 + c16 * 8);
            vd0 = *(const uint4*)(vbase + (size_t)srow * 2048 + s1 + c16 * 8);
            vd1 = *(const uint4*)(vbase + (size_t)(srow + 32) * 2048 + s1 + c16 * 8);
        }
        const unsigned short* sKc = sK[cur];
        const unsigned short* sVc = sV[cur];

        if (s0 <= qw0 + 31) {  // not fully masked for this wave
            // ---- S^T = K·Q^T via swapped mfma: q = lane&31, s = reg-pattern
            f32x16 sacc[2] = {};
            __builtin_amdgcn_s_setprio(1);
#pragma unroll
            for (int kc = 0; kc < 4; ++kc) {
#pragma unroll
                for (int ni = 0; ni < 2; ++ni) {
                    const int row = ni * 32 + l31;
                    short8 akf = *(const short8*)&sKc[row * 64 +
                                                      (((b5 + kc * 2) ^ (row & 7))
                                                       << 3)];
                    sacc[ni] = __builtin_amdgcn_mfma_f32_32x32x16_bf16(
                        akf, aq[kc], sacc[ni], 0, 0, 0);
                }
            }
            __builtin_amdgcn_s_setprio(0);

            // ---- causal mask (diagonal tiles only) ----
            const bool needMask = (s0 + 63 > qw0);  // wave-uniform
            const int qg = qw0 + l31;
            if (needMask) {
#pragma unroll
                for (int ni = 0; ni < 2; ++ni)
#pragma unroll
                    for (int reg = 0; reg < 16; ++reg) {
                        const int sg = s0 + ni * 32 + (reg & 3) + 8 * (reg >> 2) +
                                       4 * b5;
                        sacc[ni][reg] = (sg <= qg) ? sacc[ni][reg] : -INFINITY;
                    }
            }

            // ---- row max: balanced tree (fuses to v_max3), then cross-half
            float mt[16];
#pragma unroll
            for (int i = 0; i < 16; ++i)
                mt[i] = fmaxf(sacc[0][i], sacc[1][i]);
#pragma unroll
            for (int st = 8; st > 0; st >>= 1)
#pragma unroll
                for (int i = 0; i < 8; ++i)
                    if (i < st) mt[i] = fmaxf(mt[i], mt[i + st]);
            float mx = mt[0];
            mx = fmaxf(mx, __shfl_xor(mx, 32));  // lanes l<->l+32 hold same q

            // ---- defer-max ----
            const bool resc = __any(mx > m_st + THR);
            float f_l = 1.0f;
            if (resc) {
                const float mn = fmaxf(m_st, mx);
                f_l = exp2fast(m_st - mn);
                m_st = mn;
            }

            // ---- P = exp2(S - m) in-register ----
#pragma unroll
            for (int ni = 0; ni < 2; ++ni)
#pragma unroll
                for (int reg = 0; reg < 16; ++reg)
                    sacc[ni][reg] = exp2fast(sacc[ni][reg] - m_st);

            // ---- refragment P for PV: per 16-s chunk: 4 cvt_pk + 2 permlane
            short8 pa[4];
#pragma unroll
            for (int c = 0; c < 4; ++c) {
                const int ni = c >> 1;
                const int off = (c & 1) * 8;
                unsigned int pk01 = cvtpk(sacc[ni][off + 0], sacc[ni][off + 1]);
                unsigned int pk23 = cvtpk(sacc[ni][off + 2], sacc[ni][off + 3]);
                unsigned int pk45 = cvtpk(sacc[ni][off + 4], sacc[ni][off + 5]);
                unsigned int pk67 = cvtpk(sacc[ni][off + 6], sacc[ni][off + 7]);
                plswap(pk01, pk45);  // -> slot0 (pk01), slot2 (pk45)
                plswap(pk23, pk67);  // -> slot1 (pk23), slot3 (pk67)
                uint4 u = make_uint4(pk01, pk23, pk45, pk67);
                pa[c] = __builtin_bit_cast(short8, u);
            }

            // ---- rescale O / l (resc tiles only; f transposed l31->regpat)
            if (resc) {
                const int fil = __builtin_bit_cast(int, f_l);
#pragma unroll
                for (int reg = 0; reg < 16; ++reg) {
                    const int qpat = (reg & 3) + 8 * (reg >> 2) + 4 * b5;
                    const float fq = __builtin_bit_cast(
                        float, __builtin_amdgcn_ds_bpermute(
                                   (qpat + (lane & 32)) << 2, fil));
                    O0[reg] *= fq;
                    O1[reg] *= fq;
                    l_st[reg] *= fq;
                }
            }

            // ---- l += rowsum(P) via MFMA-ones; O += P @ V ----
            f32x16 lacc = {};
            __builtin_amdgcn_s_setprio(1);
#pragma unroll
            for (int c = 0; c < 4; ++c) {
                lacc = __builtin_amdgcn_mfma_f32_32x32x16_bf16(
                    pa[c], vones, lacc, 0, 0, 0);
                {
                    const int row = l31;  // di = 0
                    short8 bvf = *(const short8*)&sVc[row * 64 +
                                                      (((c * 2 + b5) ^ (row & 7))
                                                       << 3)];
                    O0 = __builtin_amdgcn_mfma_f32_32x32x16_bf16(
                        pa[c], bvf, O0, 0, 0, 0);
                }
                {
                    const int row = 32 + l31;  // di = 1
                    short8 bvf = *(const short8*)&sVc[row * 64 +
                                                      (((c * 2 + b5) ^ (row & 7))
                                                       << 3)];
                    O1 = __builtin_amdgcn_mfma_f32_32x32x16_bf16(
                        pa[c], bvf, O1, 0, 0, 0);
                }
            }
            __builtin_amdgcn_s_setprio(0);
#pragma unroll
            for (int reg = 0; reg < 16; ++reg) l_st[reg] += lacc[reg];
        }

        // write next tile into the other buffer (overlaps compute above)
        if (haveNext) {
            unsigned short* sKn = sK[cur ^ 1];
            unsigned short* sVn = sV[cur ^ 1];
            *(uint4*)&sKn[srow * 64 + swz] = kd0;
            *(uint4*)&sKn[(srow + 32) * 64 + swz] = kd1;
            *(uint4*)&sVn[srow * 64 + swz] = vd0;
            *(uint4*)&sVn[(srow + 32) * 64 + swz] = vd1;
        }
        __syncthreads();  // publish next buf + protect current buf
        cur ^= 1;
    }

    // ---- normalize + write: q = qw0 + regpat, d = di*32 + l31 ----
#pragma unroll
    for (int reg = 0; reg < 16; ++reg) {
        const int qpat = (reg & 3) + 8 * (reg >> 2) + 4 * b5;
        const float inv = 1.0f / l_st[reg];
        const size_t base = (size_t)(b * T + qw0 + qpat) * 1024 + h * 64 + l31;
        y[base] = f2bf(O0[reg] * inv);
        y[base + 32] = f2bf(O1[reg] * inv);
    }
}

extern "C" void kernel_launch(void* const* d_in, const int* in_sizes, int n_in,
                              void* d_out, int out_size, void* d_ws, size_t ws_size,
                              hipStream_t stream) {
    const float* x      = (const float*)d_in[0];
    const float* w_attn = (const float*)d_in[1];
    const float* b_attn = (const float*)d_in[2];
    const float* w_proj = (const float*)d_in[3];
    const float* b_proj = (const float*)d_in[4];

    const int C = 1024, T = 2048, H = 16;
    const int B = in_sizes[0] / (T * C);
    const int M = B * T;

    // workspace (ushorts): xb | wTa | wTp | qk | vt   (75.5 MB total)
    unsigned short* xb  = (unsigned short*)d_ws;          // M*C
    unsigned short* wTa = xb + (size_t)M * C;             // 3C x C
    unsigned short* wTp = wTa + (size_t)3 * C * C;        // C x C
    unsigned short* qkb = wTp + (size_t)C * C;            // M x 2C
    unsigned short* vtb = qkb + (size_t)M * 2 * C;        // B*1024 x T
    unsigned short* y   = xb;                             // reuse after GEMM1

    int n4 = (M * C) / 4;
    conv_f32_to_bf16<<<(n4 + 255) / 256, 256, 0, stream>>>(x, xb, n4);
    transpose_f32_to_bf16<<<dim3(3 * C / 32, C / 32), dim3(32, 8), 0, stream>>>(
        w_attn, wTa, C, 3 * C);
    transpose_f32_to_bf16<<<dim3(C / 32, C / 32), dim3(32, 8), 0, stream>>>(
        w_proj, wTp, C, C);
    gemm_bt<2><<<dim3(M / 128, (3 * C) / 128), 256, 0, stream>>>(
        xb, wTa, b_attn, (void*)qkb, vtb, M, 3 * C, C);
    attn_mfma<<<dim3((B * H) * 16), 256, 0, stream>>>(qkb, vtb, y, B * H);
    gemm_bt<0><<<dim3(M / 128, C / 128), 256, 0, stream>>>(
        y, wTp, b_proj, d_out, nullptr, M, C, C);
}

// Round 16
// 160.661 us; speedup vs baseline: 1.1122x; 1.0195x over previous
//
#include <hip/hip_runtime.h>
#include <hip/hip_bf16.h>

typedef short short8 __attribute__((ext_vector_type(8)));
typedef float f32x4 __attribute__((ext_vector_type(4)));
typedef float f32x16 __attribute__((ext_vector_type(16)));

typedef __attribute__((address_space(1))) void as1_void;
typedef __attribute__((address_space(3))) void as3_void;

__device__ __forceinline__ unsigned short f2bf(float f) {
    __hip_bfloat16 h = __float2bfloat16(f);
    return __builtin_bit_cast(unsigned short, h);
}

// fast base-2 exp (v_exp_f32)
__device__ __forceinline__ float exp2fast(float x) {
    return __builtin_amdgcn_exp2f(x);
}

// pack two f32 -> 2xbf16 in one u32 (no builtin on gfx950; T12 recipe)
__device__ __forceinline__ unsigned int cvtpk(float lo, float hi) {
    unsigned int r;
    asm("v_cvt_pk_bf16_f32 %0, %1, %2" : "=v"(r) : "v"(lo), "v"(hi));
    return r;
}

// v_permlane32_swap_b32: a_hi <-> b_lo. After: a=[a_lo|b_lo], b=[a_hi|b_hi]
// NOTE: only safe when a and b are provably-distinct values (R11 lesson).
__device__ __forceinline__ void plswap(unsigned int& a, unsigned int& b) {
    asm("v_permlane32_swap_b32 %0, %1" : "+v"(a), "+v"(b));
}

// async global->LDS, 16B per lane; lds dest = wave-uniform base + lane*16
__device__ __forceinline__ void gload16(const unsigned short* g, unsigned short* l) {
    __builtin_amdgcn_global_load_lds((as1_void*)g, (as3_void*)l, 16, 0, 0);
}

// ---- fp32 -> bf16 elementwise ----------------------------------------------
__global__ __launch_bounds__(256) void conv_f32_to_bf16(
    const float* __restrict__ in, unsigned short* __restrict__ out, int n4) {
    int i = blockIdx.x * 256 + threadIdx.x;
    if (i >= n4) return;
    float4 v = ((const float4*)in)[i];
    ushort4 o;
    o.x = f2bf(v.x); o.y = f2bf(v.y); o.z = f2bf(v.z); o.w = f2bf(v.w);
    ((ushort4*)out)[i] = o;
}

// ---- both weights: W[K][N] fp32 -> WT[N][K] bf16 in ONE launch --------------
__global__ __launch_bounds__(256) void transpose2_f32_to_bf16(
    const float* __restrict__ Wa, const float* __restrict__ Wp,
    unsigned short* __restrict__ WTa, unsigned short* __restrict__ WTp) {
    __shared__ float tile[32][33];
    const int K = 1024;
    int bx = blockIdx.x;
    const float* W;
    unsigned short* WT;
    int N, n0;
    if (bx < 96) { W = Wa; WT = WTa; N = 3072; n0 = bx * 32; }
    else         { W = Wp; WT = WTp; N = 1024; n0 = (bx - 96) * 32; }
    int tx = threadIdx.x, ty = threadIdx.y;
    int k0 = blockIdx.y * 32;
#pragma unroll
    for (int j = 0; j < 4; ++j)
        tile[ty + j * 8][tx] = W[(size_t)(k0 + ty + j * 8) * N + n0 + tx];
    __syncthreads();
#pragma unroll
    for (int j = 0; j < 4; ++j)
        WT[(size_t)(n0 + ty + j * 8) * K + k0 + tx] = f2bf(tile[tx][ty + j * 8]);
}

// ---- GEMM: C[M,N] = A[M,K]bf16 @ Bt[N,K]^T + bias --------------------------
// BK=64, global_load_lds staging with XOR-swizzled layout. MODE 0: fp32 out.
// MODE 2: qkv split: cols<1024 -> bf16 q*(0.125*log2e); 1024..2047 -> bf16 k;
//         cols>=2048 -> bf16 vt[(b*1024 + c-2048)][t] (transposed V).
template <int MODE>
__global__ __launch_bounds__(256, 2) void gemm_bt(
    const unsigned short* __restrict__ A,
    const unsigned short* __restrict__ Bt,
    const float* __restrict__ bias,
    void* __restrict__ out0,
    unsigned short* __restrict__ out1,
    int M, int N, int K) {
    __shared__ unsigned short sA[128 * 64];
    __shared__ unsigned short sB[128 * 64];
    const int tid = threadIdx.x;
    const int lane = tid & 63;
    const int w = tid >> 6;
    const int wr = (w >> 1) * 64;
    const int wc = (w & 1) * 64;
    const size_t arow0 = (size_t)blockIdx.x * 128;
    const size_t brow0 = (size_t)blockIdx.y * 128;

    const int grow = (w << 5) + (lane >> 3);
    const int gcolswz = (((lane & 7) ^ ((lane >> 3) & 7)) << 3);
    const unsigned short* pA0 = A + (arow0 + grow) * (size_t)K + gcolswz;
    const unsigned short* pB0 = Bt + (brow0 + grow) * (size_t)K + gcolswz;
    unsigned short* lA = sA + (w << 11);  // w*32*64
    unsigned short* lB = sB + (w << 11);

    f32x4 acc[4][4] = {};
    const int fr = lane & 15;
    const int g = lane >> 4;  // 0..3 -> k-chunk within 32-wide half

    for (int k0 = 0; k0 < K; k0 += 64) {
        __syncthreads();
#pragma unroll
        for (int j = 0; j < 4; ++j) {
            gload16(pA0 + (size_t)(j * 8) * K + k0, lA + j * 512);
            gload16(pB0 + (size_t)(j * 8) * K + k0, lB + j * 512);
        }
        __syncthreads();

#pragma unroll
        for (int kc = 0; kc < 2; ++kc) {
            short8 af[4], bfr[4];
#pragma unroll
            for (int i = 0; i < 4; ++i) {
                const int row = wr + i * 16 + fr;
                af[i] = *(const short8*)&sA[row * 64 +
                                            (((kc * 4 + g) ^ (row & 7)) << 3)];
            }
#pragma unroll
            for (int i = 0; i < 4; ++i) {
                const int row = wc + i * 16 + fr;
                bfr[i] = *(const short8*)&sB[row * 64 +
                                             (((kc * 4 + g) ^ (row & 7)) << 3)];
            }
#pragma unroll
            for (int mi = 0; mi < 4; ++mi)
#pragma unroll
                for (int ni = 0; ni < 4; ++ni)
                    acc[mi][ni] = __builtin_amdgcn_mfma_f32_16x16x32_bf16(
                        af[mi], bfr[ni], acc[mi][ni], 0, 0, 0);
        }
    }

    const int fq = (lane >> 4) << 2;
    if constexpr (MODE == 0) {
#pragma unroll
        for (int mi = 0; mi < 4; ++mi)
#pragma unroll
            for (int ni = 0; ni < 4; ++ni) {
                size_t r = arow0 + wr + mi * 16 + fq;
                size_t c = brow0 + wc + ni * 16 + fr;
                float bv = bias[c];
#pragma unroll
                for (int j = 0; j < 4; ++j)
                    ((float*)out0)[(r + j) * (size_t)N + c] = acc[mi][ni][j] + bv;
            }
    } else {
        const bool isv = (int)(brow0 + wc) >= 2048;
        if (isv) {
#pragma unroll
            for (int mi = 0; mi < 4; ++mi)
#pragma unroll
                for (int ni = 0; ni < 4; ++ni) {
                    int c = (int)brow0 + wc + ni * 16 + fr;
                    float bv = bias[c];
                    int cv = c - 2048;
                    int r0 = (int)arow0 + wr + mi * 16 + fq;
                    int bb = r0 >> 11, t0 = r0 & 2047;
                    unsigned int lo = (unsigned int)f2bf(acc[mi][ni][0] + bv) |
                                      ((unsigned int)f2bf(acc[mi][ni][1] + bv) << 16);
                    unsigned int hi = (unsigned int)f2bf(acc[mi][ni][2] + bv) |
                                      ((unsigned int)f2bf(acc[mi][ni][3] + bv) << 16);
                    *(uint2*)&out1[(((size_t)(bb * 1024 + cv)) << 11) + t0] =
                        make_uint2(lo, hi);
                }
        } else {
            // q columns: fold 1/sqrt(D) * log2(e) so attention runs in exp2 domain
            const float qs = ((int)(brow0 + wc) < 1024) ? 0.125f * 1.4426950408889634f
                                                        : 1.0f;
#pragma unroll
            for (int mi = 0; mi < 4; ++mi)
#pragma unroll
                for (int ni = 0; ni < 4; ++ni) {
                    size_t r = arow0 + wr + mi * 16 + fq;
                    size_t c = brow0 + wc + ni * 16 + fr;
                    float bv = bias[c];
#pragma unroll
                    for (int j = 0; j < 4; ++j)
                        ((unsigned short*)out0)[(r + j) * 2048 + c] =
                            f2bf((acc[mi][ni][j] + bv) * qs);
                }
        }
    }
}

// ---- MFMA flash attention (swapped QK^T, 32x32x16, in-register softmax) ----
// Block: ONE 128-row q-tile (4 waves x 32 rows); grid = BH*16, heavy-first.
// s-tiles of 64; K,V^T double-buffered in swizzled LDS (one barrier/tile).
// K register-prefetch is 2-DEEP (named even/odd sets, rule-#20-safe): K(t+1)'s
// LDS write uses regs loaded a full iteration earlier, so its vmcnt is counted
// not draining; V stays 1-deep (consumed late in the tile). l accumulates
// directly as the MFMA-ones C operand. Defer-max rescale (T13).
__global__ __launch_bounds__(256, 3) void attn_mfma(
    const unsigned short* __restrict__ qk,  // [B*T][2048] bf16 (q*scale | k)
    const unsigned short* __restrict__ vt,  // [(b*1024+h*64+d)][T] bf16
    unsigned short* __restrict__ y,         // [B*T][1024] bf16
    int BH) {
    constexpr int T = 2048;
    constexpr float THR = 8.0f;  // exp2-domain defer threshold

    __shared__ __align__(16) unsigned short sK[2][64 * 64];
    __shared__ __align__(16) unsigned short sV[2][64 * 64];  // V^T tile [d][s]

    const int tid = threadIdx.x;
    const int lane = tid & 63;
    const int w = tid >> 6;
    const int l31 = lane & 31;
    const int b5 = lane >> 5;

    const int bh = blockIdx.x % BH;
    const int qt = 15 - blockIdx.x / BH;  // heavy q-tiles dispatched first
    const int b = bh >> 4;
    const int h = bh & 15;
    const int q0 = qt << 7;
    const int qw0 = q0 + w * 32;

    const unsigned short* kbase = qk + ((size_t)(b * T)) * 2048 + 1024 + h * 64;
    const unsigned short* vbase = vt + ((size_t)(b * 1024 + h * 64)) * 2048;

    const int srow = tid >> 3;   // staging row 0..31 (+32)
    const int c16 = tid & 7;     // 16B column within 128B row
    const int swz = ((c16 ^ (srow & 7)) << 3);

    short8 vones;
#pragma unroll
    for (int i = 0; i < 8; ++i) vones[i] = (short)0x3F80;  // bf16 1.0

    // Q fragments (B-operand): row q = qw0+l31, k(d) = b5*8 + kc*16
    short8 aq[4];
    {
        const unsigned short* qbase =
            qk + ((size_t)(b * T + qw0 + l31)) * 2048 + h * 64;
#pragma unroll
        for (int kc = 0; kc < 4; ++kc)
            aq[kc] = *(const short8*)(qbase + b5 * 8 + kc * 16);
    }

    f32x16 O0 = {}, O1 = {};
    f32x16 l_st = {};
    float m_st = -1e30f;

    const int nt = (q0 + 128) >> 6;

    // K 2-deep prefetch: set A holds even tiles, set B odd tiles.
    uint4 kA0, kA1, kB0, kB1, vd0, vd1;
    // prologue: tile 0 -> set A + LDS buf0; tile 1 -> set B (regs only)
    kA0 = *(const uint4*)(kbase + (size_t)(srow) * 2048 + c16 * 8);
    kA1 = *(const uint4*)(kbase + (size_t)(srow + 32) * 2048 + c16 * 8);
    vd0 = *(const uint4*)(vbase + (size_t)srow * 2048 + c16 * 8);
    vd1 = *(const uint4*)(vbase + (size_t)(srow + 32) * 2048 + c16 * 8);
    *(uint4*)&sK[0][srow * 64 + swz] = kA0;
    *(uint4*)&sK[0][(srow + 32) * 64 + swz] = kA1;
    *(uint4*)&sV[0][srow * 64 + swz] = vd0;
    *(uint4*)&sV[0][(srow + 32) * 64 + swz] = vd1;
    kB0 = *(const uint4*)(kbase + (size_t)(64 + srow) * 2048 + c16 * 8);
    kB1 = *(const uint4*)(kbase + (size_t)(64 + srow + 32) * 2048 + c16 * 8);
    __syncthreads();

    for (int it = 0; it < nt; ++it) {
        const int s0 = it << 6;
        const bool haveNext = (it + 1 < nt);
        const bool have2 = (it + 2 < nt);
        // reload the set that held tile `it` with tile it+2 (its LDS write
        // happened last iteration, so the regs are free); load V for it+1.
        if (it & 1) {
            if (have2) {
                const int s2 = s0 + 128;
                kB0 = *(const uint4*)(kbase + (size_t)(s2 + srow) * 2048 + c16 * 8);
                kB1 = *(const uint4*)(kbase + (size_t)(s2 + srow + 32) * 2048 +
                                      c16 * 8);
            }
        } else {
            if (have2) {
                const int s2 = s0 + 128;
                kA0 = *(const uint4*)(kbase + (size_t)(s2 + srow) * 2048 + c16 * 8);
                kA1 = *(const uint4*)(kbase + (size_t)(s2 + srow + 32) * 2048 +
                                      c16 * 8);
            }
        }
        if (haveNext) {
            const int s1 = s0 + 64;
            vd0 = *(const uint4*)(vbase + (size_t)srow * 2048 + s1 + c16 * 8);
            vd1 = *(const uint4*)(vbase + (size_t)(srow + 32) * 2048 + s1 + c16 * 8);
        }
        const unsigned short* sKc = sK[it & 1];
        const unsigned short* sVc = sV[it & 1];

        if (s0 <= qw0 + 31) {  // not fully masked for this wave
            // ---- S^T = K·Q^T via swapped mfma: q = lane&31, s = reg-pattern
            f32x16 sacc[2] = {};
            __builtin_amdgcn_s_setprio(1);
#pragma unroll
            for (int kc = 0; kc < 4; ++kc) {
#pragma unroll
                for (int ni = 0; ni < 2; ++ni) {
                    const int row = ni * 32 + l31;
                    short8 akf = *(const short8*)&sKc[row * 64 +
                                                      (((b5 + kc * 2) ^ (row & 7))
                                                       << 3)];
                    sacc[ni] = __builtin_amdgcn_mfma_f32_32x32x16_bf16(
                        akf, aq[kc], sacc[ni], 0, 0, 0);
                }
            }
            __builtin_amdgcn_s_setprio(0);

            // ---- causal mask (diagonal tiles only) ----
            const bool needMask = (s0 + 63 > qw0);  // wave-uniform
            const int qg = qw0 + l31;
            if (needMask) {
#pragma unroll
                for (int ni = 0; ni < 2; ++ni)
#pragma unroll
                    for (int reg = 0; reg < 16; ++reg) {
                        const int sg = s0 + ni * 32 + (reg & 3) + 8 * (reg >> 2) +
                                       4 * b5;
                        sacc[ni][reg] = (sg <= qg) ? sacc[ni][reg] : -INFINITY;
                    }
            }

            // ---- row max: balanced tree (fuses to v_max3), then cross-half
            float mt[16];
#pragma unroll
            for (int i = 0; i < 16; ++i)
                mt[i] = fmaxf(sacc[0][i], sacc[1][i]);
#pragma unroll
            for (int st = 8; st > 0; st >>= 1)
#pragma unroll
                for (int i = 0; i < 8; ++i)
                    if (i < st) mt[i] = fmaxf(mt[i], mt[i + st]);
            float mx = mt[0];
            mx = fmaxf(mx, __shfl_xor(mx, 32));  // lanes l<->l+32 hold same q

            // ---- defer-max ----
            const bool resc = __any(mx > m_st + THR);
            float f_l = 1.0f;
            if (resc) {
                const float mn = fmaxf(m_st, mx);
                f_l = exp2fast(m_st - mn);
                m_st = mn;
            }

            // ---- P = exp2(S - m) in-register ----
#pragma unroll
            for (int ni = 0; ni < 2; ++ni)
#pragma unroll
                for (int reg = 0; reg < 16; ++reg)
                    sacc[ni][reg] = exp2fast(sacc[ni][reg] - m_st);

            // ---- refragment P for PV: per 16-s chunk: 4 cvt_pk + 2 permlane
            short8 pa[4];
#pragma unroll
            for (int c = 0; c < 4; ++c) {
                const int ni = c >> 1;
                const int off = (c & 1) * 8;
                unsigned int pk01 = cvtpk(sacc[ni][off + 0], sacc[ni][off + 1]);
                unsigned int pk23 = cvtpk(sacc[ni][off + 2], sacc[ni][off + 3]);
                unsigned int pk45 = cvtpk(sacc[ni][off + 4], sacc[ni][off + 5]);
                unsigned int pk67 = cvtpk(sacc[ni][off + 6], sacc[ni][off + 7]);
                plswap(pk01, pk45);  // -> slot0 (pk01), slot2 (pk45)
                plswap(pk23, pk67);  // -> slot1 (pk23), slot3 (pk67)
                uint4 u = make_uint4(pk01, pk23, pk45, pk67);
                pa[c] = __builtin_bit_cast(short8, u);
            }

            // ---- rescale O / l (resc tiles only; f transposed l31->regpat)
            if (resc) {
                const int fil = __builtin_bit_cast(int, f_l);
#pragma unroll
                for (int reg = 0; reg < 16; ++reg) {
                    const int qpat = (reg & 3) + 8 * (reg >> 2) + 4 * b5;
                    const float fq = __builtin_bit_cast(
                        float, __builtin_amdgcn_ds_bpermute(
                                   (qpat + (lane & 32)) << 2, fil));
                    O0[reg] *= fq;
                    O1[reg] *= fq;
                    l_st[reg] *= fq;
                }
            }

            // ---- l += rowsum(P) via MFMA-ones (accumulate in C); O += P@V --
            __builtin_amdgcn_s_setprio(1);
#pragma unroll
            for (int c = 0; c < 4; ++c) {
                l_st = __builtin_amdgcn_mfma_f32_32x32x16_bf16(
                    pa[c], vones, l_st, 0, 0, 0);
                {
                    const int row = l31;  // di = 0
                    short8 bvf = *(const short8*)&sVc[row * 64 +
                                                      (((c * 2 + b5) ^ (row & 7))
                                                       << 3)];
                    O0 = __builtin_amdgcn_mfma_f32_32x32x16_bf16(
                        pa[c], bvf, O0, 0, 0, 0);
                }
                {
                    const int row = 32 + l31;  // di = 1
                    short8 bvf = *(const short8*)&sVc[row * 64 +
                                                      (((c * 2 + b5) ^ (row & 7))
                                                       << 3)];
                    O1 = __builtin_amdgcn_mfma_f32_32x32x16_bf16(
                        pa[c], bvf, O1, 0, 0, 0);
                }
            }
            __builtin_amdgcn_s_setprio(0);
        }

        // write tile it+1 into the other buffer: K regs were loaded a full
        // iteration ago (counted vmcnt, already landed); V loaded this iter.
        if (haveNext) {
            unsigned short* sKn = sK[(it + 1) & 1];
            unsigned short* sVn = sV[(it + 1) & 1];
            if (it & 1) {
                *(uint4*)&sKn[srow * 64 + swz] = kA0;
                *(uint4*)&sKn[(srow + 32) * 64 + swz] = kA1;
            } else {
                *(uint4*)&sKn[srow * 64 + swz] = kB0;
                *(uint4*)&sKn[(srow + 32) * 64 + swz] = kB1;
            }
            *(uint4*)&sVn[srow * 64 + swz] = vd0;
            *(uint4*)&sVn[(srow + 32) * 64 + swz] = vd1;
        }
        __syncthreads();  // publish next buf + protect current buf
    }

    // ---- normalize + write: q = qw0 + regpat, d = di*32 + l31 ----
#pragma unroll
    for (int reg = 0; reg < 16; ++reg) {
        const int qpat = (reg & 3) + 8 * (reg >> 2) + 4 * b5;
        const float inv = 1.0f / l_st[reg];
        const size_t base = (size_t)(b * T + qw0 + qpat) * 1024 + h * 64 + l31;
        y[base] = f2bf(O0[reg] * inv);
        y[base + 32] = f2bf(O1[reg] * inv);
    }
}

extern "C" void kernel_launch(void* const* d_in, const int* in_sizes, int n_in,
                              void* d_out, int out_size, void* d_ws, size_t ws_size,
                              hipStream_t stream) {
    const float* x      = (const float*)d_in[0];
    const float* w_attn = (const float*)d_in[1];
    const float* b_attn = (const float*)d_in[2];
    const float* w_proj = (const float*)d_in[3];
    const float* b_proj = (const float*)d_in[4];

    const int C = 1024, T = 2048, H = 16;
    const int B = in_sizes[0] / (T * C);
    const int M = B * T;

    // workspace (ushorts): xb | wTa | wTp | qk | vt   (75.5 MB total)
    unsigned short* xb  = (unsigned short*)d_ws;          // M*C
    unsigned short* wTa = xb + (size_t)M * C;             // 3C x C
    unsigned short* wTp = wTa + (size_t)3 * C * C;        // C x C
    unsigned short* qkb = wTp + (size_t)C * C;            // M x 2C
    unsigned short* vtb = qkb + (size_t)M * 2 * C;        // B*1024 x T
    unsigned short* y   = xb;                             // reuse after GEMM1

    int n4 = (M * C) / 4;
    conv_f32_to_bf16<<<(n4 + 255) / 256, 256, 0, stream>>>(x, xb, n4);
    transpose2_f32_to_bf16<<<dim3(128, 32), dim3(32, 8), 0, stream>>>(
        w_attn, w_proj, wTa, wTp);
    gemm_bt<2><<<dim3(M / 128, (3 * C) / 128), 256, 0, stream>>>(
        xb, wTa, b_attn, (void*)qkb, vtb, M, 3 * C, C);
    attn_mfma<<<dim3((B * H) * 16), 256, 0, stream>>>(qkb, vtb, y, B * H);
    gemm_bt<0><<<dim3(M / 128, C / 128), 256, 0, stream>>>(
        y, wTp, b_proj, d_out, nullptr, M, C, C);
}